// Round 9
// baseline (421.409 us; speedup 1.0000x reference)
//
#include <hip/hip_runtime.h>
#include <hip/hip_bf16.h>
#include <stdint.h>

// Problem constants: B=16, XL=YL=D=1024
#define NBATCH 16
#define NDIM   1024
#define NEL    (16u*1024u*1024u)

typedef __attribute__((ext_vector_type(8))) short bf16x8;
typedef __attribute__((ext_vector_type(4))) short short4_t;
typedef __attribute__((ext_vector_type(4))) float f32x4;
typedef __attribute__((ext_vector_type(4))) int   i32x4;

__device__ __forceinline__ short f2bf(float f){
  union { __hip_bfloat16 b; short s; } u;
  u.b = __float2bfloat16(f);   // RNE
  return u.s;
}
__device__ __forceinline__ float bf2f(short s){
  union { short s; __hip_bfloat16 b; } u;
  u.s = s;
  return __bfloat162float(u.b);
}

// -------- xs: f32 -> bf16 hi + lo
__global__ __launch_bounds__(256) void k_split(const float* __restrict__ in,
                                               short* __restrict__ hi,
                                               short* __restrict__ lo)
{
  const size_t i = ((size_t)blockIdx.x * 256 + threadIdx.x) * 4;
  f32x4 v = *(const f32x4*)(in + i);
  short4_t h, l;
  #pragma unroll
  for (int j = 0; j < 4; j++){
    short hb = f2bf(v[j]);
    h[j] = hb;
    l[j] = f2bf(v[j] - bf2f(hb));
  }
  *(short4_t*)(hi + i) = h;
  *(short4_t*)(lo + i) = l;
}

// -------- ys: one read pass -> ys_hi, ys_lo (straight) + ysT bf16 (transposed)
__global__ __launch_bounds__(512) void k_split_ysT(const float* __restrict__ ys,
                                                   short* __restrict__ hi,
                                                   short* __restrict__ lo,
                                                   short* __restrict__ ysT)
{
  __shared__ float t[64][65];
  const int b  = blockIdx.z;
  const int y0 = blockIdx.y * 64;
  const int d0 = blockIdx.x * 64;
  const int lx = threadIdx.x;          // 0..63
  const int ly = threadIdx.y;          // 0..7
  const float* src = ys + ((size_t)b * NDIM + y0) * NDIM + d0;
  short* ph = hi + ((size_t)b * NDIM + y0) * NDIM + d0;
  short* pl = lo + ((size_t)b * NDIM + y0) * NDIM + d0;
  #pragma unroll
  for (int r = ly; r < 64; r += 8){
    float v = src[(size_t)r * NDIM + lx];
    short hb = f2bf(v);
    ph[(size_t)r * NDIM + lx] = hb;
    pl[(size_t)r * NDIM + lx] = f2bf(v - bf2f(hb));
    t[r][lx] = v;
  }
  __syncthreads();
  short* pt = ysT + ((size_t)b * NDIM + d0) * NDIM + y0;
  #pragma unroll
  for (int r = ly; r < 64; r += 8)
    pt[(size_t)r * NDIM + lx] = f2bf(t[lx][r]);   // banks (lx+r)%32: 2-way, free
}

// -------- global->LDS direct copy, 16B/lane (dst wave-uniform; HW adds lane*16)
__device__ __forceinline__ void gload_lds16(const short* g, short* l){
  __builtin_amdgcn_global_load_lds((const __attribute__((address_space(1))) void*)g,
                                   (__attribute__((address_space(3))) void*)l,
                                   16, 0, 0);
}

#define MFMA_BF16(d, a, b) d = __builtin_amdgcn_mfma_f32_16x16x32_bf16(a, b, d, 0, 0, 0)

// ==================== 256x256-tile 8-wave single-barrier GEMM ====================
// C[b] (256x256 tile) += A (M x Kv row-major) * B^T (N x Kv row-major), Kv = nt*32.
// Virtual-K segments of 1024 map split-bf16 GEMM1 to plain bf16 with Kv=3072.
// 512 threads = 8 waves (2 row x 4 col), per-wave out 128x64 = acc[8][4] f32x4.
// LDS: 4-deep ring of K-tiles (A 256x32 + B 256x32 bf16 = 32 KB) = 128 KB.
//
// ONE barrier per K-tile (round-5 post-mortem: 4 barriers/tile left MfmaUtil at 35%,
// ~2000 stall cyc/tile). Per tile:
//   {12 ds_read | stage A,B(t+3) | vmcnt(8/4/0) | lgkm(0) | sched_barrier |
//    setprio(1) 32 MFMA setprio(0) | barrier}
// Safety:
//  - ds_reads are wave-private (LDS->own VGPR->own MFMA): no barrier needed pre-MFMA.
//  - RAW(slot t+1): each wave's vmcnt retires its OWN 4 loads for tile t+1, then the
//    tile-t barrier makes all waves' loads globally visible before tile t+1 reads.
//  - WAR(slot (t-1)&3, stage targets it at tile t): every wave executed lgkm(0)
//    (own tile t-1 reads complete) before its tile t-1 barrier; stages issue after.
//  - asm "memory" clobbers fence the gload_lds intrinsics; MFMA hoisting past the
//    waits is harmless (register deps force compiler's own lgkm before first use).
// vmcnt ladder: 12 in flight after stage -> vmcnt(8) retires tile t+1's 4 loads;
// tail: vmcnt(4) at nt-3, vmcnt(0) at nt-2 (re-derived, matches round-3 audit).
// Stage->read k-slot swizzle phys = slot ^ ((row>>1)&3): 0 conflicts measured (r2/r5).
template<int TAG>
__global__ __launch_bounds__(512, 2) void k_gemm256(
    const short* __restrict__ A0, const short* __restrict__ A1, const short* __restrict__ A2,
    const short* __restrict__ B0, const short* __restrict__ B1, const short* __restrict__ B2,
    float* __restrict__ C, int nt)
{
  __shared__ __align__(16) short lds[4][2][2][4096];  // [ring][A/B][half][128*32]

  const int tid  = threadIdx.x;
  const int lane = tid & 63;
  const int wid  = tid >> 6;      // 0..7
  const int wr   = wid >> 2;      // 0..1  (row half)
  const int wcl  = wid & 3;       // 0..3  (col quarter)

  // XCD-chunked bijective swizzle: 256 blocks, 8 XCDs -> each XCD owns 2 full batches
  const int lid = blockIdx.x;
  const int swz = (lid & 7) * 32 + (lid >> 3);
  const int bz = swz >> 4, by = (swz >> 2) & 3, bx = swz & 3;

  const size_t bofs = (size_t)bz * NDIM * NDIM;
  const size_t arow = (size_t)bx * 256 * NDIM;
  const size_t brow = (size_t)by * 256 * NDIM;
  const short* Ap0 = A0 + bofs + arow; const short* Ap1 = A1 + bofs + arow;
  const short* Ap2 = A2 + bofs + arow;
  const short* Bp0 = B0 + bofs + brow; const short* Bp1 = B1 + bofs + brow;
  const short* Bp2 = B2 + bofs + brow;

  const int srow = tid >> 2;                              // staging row 0..127
  const int sslot = (tid & 3) ^ ((srow >> 1) & 3);        // pre-swizzled source k-slot

  auto stageT = [&](int kt, int sel){
    const int r = kt & 3;
    const int seg = kt >> 5;                              // 32 tiles per K-segment
    const int k0 = (kt & 31) * 32;
    const short* P = sel ? (seg == 0 ? Bp0 : (seg == 1 ? Bp1 : Bp2))
                         : (seg == 0 ? Ap0 : (seg == 1 ? Ap1 : Ap2));
    short* dbase = &lds[r][sel][0][0] + wid * 512;        // wave-uniform
    #pragma unroll
    for (int h = 0; h < 2; h++)
      gload_lds16(P + (size_t)(h * 128 + srow) * NDIM + k0 + sslot * 8,
                  dbase + h * 4096);
  };

  auto rdA = [&](int kt, int m) -> bf16x8 {
    const int rl = m * 16 + (lane & 15);
    const int p  = (lane >> 4) ^ ((rl >> 1) & 3);
    return *(const bf16x8*)(&lds[kt & 3][0][wr][0] + rl * 32 + p * 8);
  };
  auto rdB = [&](int kt, int n) -> bf16x8 {
    const int rb = wcl * 64 + n * 16 + (lane & 15);
    const int p  = (lane >> 4) ^ ((rb >> 1) & 3);
    return *(const bf16x8*)(&lds[kt & 3][1][rb >> 7][0] + (rb & 127) * 32 + p * 8);
  };

  f32x4 acc[8][4] = {};

  // prologue: stage tiles 0,1,2 (12 loads); retire tile 0's 4, then barrier
  stageT(0, 0); stageT(0, 1);
  stageT(1, 0); stageT(1, 1);
  stageT(2, 0); stageT(2, 1);
  asm volatile("s_waitcnt vmcnt(8)" ::: "memory");
  __builtin_amdgcn_s_barrier();

  for (int t = 0; t < nt; ++t){
    // 12 ds_read_b128: full tile's fragments into registers
    bf16x8 af[4], ag[4], bfr[4];
    #pragma unroll
    for (int m = 0; m < 4; m++) af[m] = rdA(t, m);
    #pragma unroll
    for (int m = 0; m < 4; m++) ag[m] = rdA(t, m + 4);
    #pragma unroll
    for (int n = 0; n < 4; n++) bfr[n] = rdB(t, n);

    // stage tile t+3 into ring slot (t-1)&3 (WAR-safe: see header)
    if (t + 3 < nt){ stageT(t + 3, 0); stageT(t + 3, 1); }

    // counted vmcnt: confirm tile t+1's loads landed (never 0 mid-loop)
    if (t + 1 < nt){
      if (t + 3 < nt)      asm volatile("s_waitcnt vmcnt(8)" ::: "memory");
      else if (t + 2 < nt) asm volatile("s_waitcnt vmcnt(4)" ::: "memory");
      else                 asm volatile("s_waitcnt vmcnt(0)" ::: "memory");
    }
    // own reads complete (required before the tile-end barrier for WAR proof)
    asm volatile("s_waitcnt lgkmcnt(0)" ::: "memory");
    __builtin_amdgcn_sched_barrier(0);

    __builtin_amdgcn_s_setprio(1);
    #pragma unroll
    for (int m = 0; m < 4; m++)
      #pragma unroll
      for (int n = 0; n < 4; n++)
        MFMA_BF16(acc[m][n], af[m], bfr[n]);
    #pragma unroll
    for (int m = 0; m < 4; m++)
      #pragma unroll
      for (int n = 0; n < 4; n++)
        MFMA_BF16(acc[m + 4][n], ag[m], bfr[n]);
    __builtin_amdgcn_s_setprio(0);

    __builtin_amdgcn_s_barrier();   // single per-tile gate (RAW t+1 / WAR t+4)
  }

  // epilogue: C/D layout col=lane&15, row=(lane>>4)*4+reg (m89)
  float* Cb = C + bofs;
  const int row0 = bx * 256 + wr * 128 + (lane >> 4) * 4;
  const int col0 = by * 256 + wcl * 64 + (lane & 15);
  #pragma unroll
  for (int m = 0; m < 8; m++)
    #pragma unroll
    for (int n = 0; n < 4; n++)
      #pragma unroll
      for (int r = 0; r < 4; r++)
        Cb[(size_t)(row0 + m * 16 + r) * NDIM + col0 + n * 16] = acc[m][n][r];
}

// -------- masked softmax over last dim, in-place on f32 weight; also emits bf16 copy.
__global__ __launch_bounds__(256) void k_softmax(float* __restrict__ w,
                                                 short* __restrict__ wbf,
                                                 const int* __restrict__ mask)
{
  const int gw   = blockIdx.x * 4 + (threadIdx.x >> 6);
  const int b    = gw >> 10;
  const int x    = gw & 1023;
  const int lane = threadIdx.x & 63;
  float* row  = w   + ((size_t)b * NDIM + x) * NDIM;
  short* rowb = wbf + ((size_t)b * NDIM + x) * NDIM;
  const int* mrow = mask + b * NDIM;

  f32x4 v[4]; i32x4 mk[4];
  float mx = -INFINITY;
  #pragma unroll
  for (int j = 0; j < 4; j++){
    const int c = j * 256 + lane * 4;
    v[j]  = *(const f32x4*)(row + c);
    mk[j] = *(const i32x4*)(mrow + c);
    #pragma unroll
    for (int e = 0; e < 4; e++)
      if (mk[j][e]) mx = fmaxf(mx, v[j][e]);
  }
  #pragma unroll
  for (int off = 32; off >= 1; off >>= 1) mx = fmaxf(mx, __shfl_xor(mx, off));

  float sum = 0.f;
  #pragma unroll
  for (int j = 0; j < 4; j++)
    #pragma unroll
    for (int e = 0; e < 4; e++){
      const float p = mk[j][e] ? __expf(v[j][e] - mx) : 0.f;
      v[j][e] = p; sum += p;
    }
  #pragma unroll
  for (int off = 32; off >= 1; off >>= 1) sum += __shfl_xor(sum, off);
  const float inv = sum > 0.f ? 1.f / sum : 0.f;

  #pragma unroll
  for (int j = 0; j < 4; j++){
    const int c = j * 256 + lane * 4;
    f32x4 o; short4_t ob;
    #pragma unroll
    for (int e = 0; e < 4; e++){
      const float p = v[j][e] * inv;
      o[e] = p; ob[e] = f2bf(p);
    }
    *(f32x4*)(row + c)  = o;
    *(short4_t*)(rowb + c) = ob;
  }
}

extern "C" void kernel_launch(void* const* d_in, const int* in_sizes, int n_in,
                              void* d_out, int out_size, void* d_ws, size_t ws_size,
                              hipStream_t stream)
{
  const float* xs   = (const float*)d_in[0];
  const float* ys   = (const float*)d_in[1];
  const int*   mask = (const int*)d_in[2];

  float* emb = (float*)d_out;            // [16,1024,1024] f32
  float* wgt = emb + (size_t)NEL;        // [16,1024,1024] f32

  // workspace (5 x NEL shorts = 168 MB)
  short* xs_hi = (short*)d_ws;
  short* xs_lo = xs_hi + NEL;
  short* ys_hi = xs_lo + NEL;
  short* ys_lo = ys_hi + NEL;
  short* ysT   = ys_lo + NEL;            // [b][d][y] bf16
  short* w_bf  = xs_hi;                  // alias: xs_hi/lo dead after GEMM1

  // 1. convert inputs (ys: split + transpose fused, single read pass)
  k_split<<<NEL / 1024, 256, 0, stream>>>(xs, xs_hi, xs_lo);
  k_split_ysT<<<dim3(16, 16, NBATCH), dim3(64, 8), 0, stream>>>(ys, ys_hi, ys_lo, ysT);
  // 2. scores = xs @ ys^T via virtual K=3072: hi*hi + hi*lo + lo*hi
  k_gemm256<0><<<256, 512, 0, stream>>>(xs_hi, xs_hi, xs_lo,
                                        ys_hi, ys_lo, ys_hi, wgt, 96);
  // 3. masked softmax in-place (+ bf16 copy into xs_hi region)
  k_softmax<<<(NBATCH * NDIM) / 4, 256, 0, stream>>>(wgt, w_bf, mask);
  // 4. emb = weight @ ys = w_bf @ ysT^T  (plain bf16, K=1024)
  k_gemm256<1><<<256, 512, 0, stream>>>(w_bf, w_bf, w_bf,
                                        ysT, ysT, ysT, emb, 32);
}

// Round 10
// 416.599 us; speedup vs baseline: 1.0115x; 1.0115x over previous
//
#include <hip/hip_runtime.h>
#include <hip/hip_bf16.h>
#include <stdint.h>

// Problem constants: B=16, XL=YL=D=1024
#define NBATCH 16
#define NDIM   1024
#define NEL    (16u*1024u*1024u)

typedef __attribute__((ext_vector_type(8))) short bf16x8;
typedef __attribute__((ext_vector_type(4))) short short4_t;
typedef __attribute__((ext_vector_type(4))) float f32x4;
typedef __attribute__((ext_vector_type(4))) int   i32x4;

__device__ __forceinline__ short f2bf(float f){
  union { __hip_bfloat16 b; short s; } u;
  u.b = __float2bfloat16(f);   // RNE
  return u.s;
}
__device__ __forceinline__ float bf2f(short s){
  union { short s; __hip_bfloat16 b; } u;
  u.s = s;
  return __bfloat162float(u.b);
}

// -------- xs: f32 -> bf16 hi + lo
__global__ __launch_bounds__(256) void k_split(const float* __restrict__ in,
                                               short* __restrict__ hi,
                                               short* __restrict__ lo)
{
  const size_t i = ((size_t)blockIdx.x * 256 + threadIdx.x) * 4;
  f32x4 v = *(const f32x4*)(in + i);
  short4_t h, l;
  #pragma unroll
  for (int j = 0; j < 4; j++){
    short hb = f2bf(v[j]);
    h[j] = hb;
    l[j] = f2bf(v[j] - bf2f(hb));
  }
  *(short4_t*)(hi + i) = h;
  *(short4_t*)(lo + i) = l;
}

// -------- ys: one read pass -> ys_hi, ys_lo (straight) + ysT bf16 (transposed)
__global__ __launch_bounds__(512) void k_split_ysT(const float* __restrict__ ys,
                                                   short* __restrict__ hi,
                                                   short* __restrict__ lo,
                                                   short* __restrict__ ysT)
{
  __shared__ float t[64][65];
  const int b  = blockIdx.z;
  const int y0 = blockIdx.y * 64;
  const int d0 = blockIdx.x * 64;
  const int lx = threadIdx.x;          // 0..63
  const int ly = threadIdx.y;          // 0..7
  const float* src = ys + ((size_t)b * NDIM + y0) * NDIM + d0;
  short* ph = hi + ((size_t)b * NDIM + y0) * NDIM + d0;
  short* pl = lo + ((size_t)b * NDIM + y0) * NDIM + d0;
  #pragma unroll
  for (int r = ly; r < 64; r += 8){
    float v = src[(size_t)r * NDIM + lx];
    short hb = f2bf(v);
    ph[(size_t)r * NDIM + lx] = hb;
    pl[(size_t)r * NDIM + lx] = f2bf(v - bf2f(hb));
    t[r][lx] = v;
  }
  __syncthreads();
  short* pt = ysT + ((size_t)b * NDIM + d0) * NDIM + y0;
  #pragma unroll
  for (int r = ly; r < 64; r += 8)
    pt[(size_t)r * NDIM + lx] = f2bf(t[lx][r]);   // banks (lx+r)%32: 2-way, free
}

// -------- global->LDS direct copy, 16B/lane (dst wave-uniform; HW adds lane*16)
__device__ __forceinline__ void gload_lds16(const short* g, short* l){
  __builtin_amdgcn_global_load_lds((const __attribute__((address_space(1))) void*)g,
                                   (__attribute__((address_space(3))) void*)l,
                                   16, 0, 0);
}

#define MFMA_BF16(d, a, b) d = __builtin_amdgcn_mfma_f32_16x16x32_bf16(a, b, d, 0, 0, 0)
#define SBAR() __builtin_amdgcn_sched_barrier(0)

// ==================== 256x256-tile 8-wave overlapped-wait GEMM ====================
// C[b] (256x256 tile) += A (M x Kv row-major) * B^T (N x Kv row-major), Kv = nt*32.
// Virtual-K segments of 1024 map split-bf16 GEMM1 to plain bf16 with Kv=3072.
// 512 threads = 8 waves (2 row x 4 col), per-wave out 128x64 = acc[8][4] f32x4.
// LDS: 4-deep ring of K-tiles (A 256x32 + B 256x32 bf16 = 32 KB) = 128 KB.
//
// Round-9 post-mortem: barrier count (4 vs 1 per tile) changed NOTHING (both 117us,
// MfmaUtil ~36.5%). The cost is strict ALTERNATION: all-waves-read (LDS pipe ~1150
// cyc/tile) then lgkm(0) then all-waves-MFMA (~1240 cyc) -- forced by my explicit
// lgkm(0)+sched_barrier before all MFMAs. Fix: GRADED lgkm waits (zero VGPR cost):
//   reads pinned in order [af0,af1,bfr0-3 | af2,af3 | ag0-3], stage loads issued early;
//   lgkm(6) -> 8 MFMA  (remaining 6 reads + 4 stage loads run under these)
//   lgkm(4) -> 8 MFMA
//   vmcnt ladder + lgkm(0) -> 16 MFMA -> barrier
// Correctness: frag reads are IR-visible, so the compiler's own dep-waits backstop
// any wait my asm understates (worst case = baseline perf, not corruption).
// WAR: lgkm(0) still precedes each tile-end barrier. RAW: vmcnt ladder unchanged
// (12 in flight, vmcnt(8) retires tile t+1; tail 4->0). Swizzle: phys-slot =
// slot ^ ((row>>1)&3), measured 0 conflicts (r2/r5/r9).
template<int TAG>
__global__ __launch_bounds__(512, 2) void k_gemm256(
    const short* __restrict__ A0, const short* __restrict__ A1, const short* __restrict__ A2,
    const short* __restrict__ B0, const short* __restrict__ B1, const short* __restrict__ B2,
    float* __restrict__ C, int nt)
{
  __shared__ __align__(16) short lds[4][2][2][4096];  // [ring][A/B][half][128*32]

  const int tid  = threadIdx.x;
  const int lane = tid & 63;
  const int wid  = tid >> 6;      // 0..7
  const int wr   = wid >> 2;      // 0..1  (row half)
  const int wcl  = wid & 3;       // 0..3  (col quarter)

  // XCD-chunked bijective swizzle: 256 blocks, 8 XCDs -> each XCD owns 2 full batches
  const int lid = blockIdx.x;
  const int swz = (lid & 7) * 32 + (lid >> 3);
  const int bz = swz >> 4, by = (swz >> 2) & 3, bx = swz & 3;

  const size_t bofs = (size_t)bz * NDIM * NDIM;
  const size_t arow = (size_t)bx * 256 * NDIM;
  const size_t brow = (size_t)by * 256 * NDIM;
  const short* Ap0 = A0 + bofs + arow; const short* Ap1 = A1 + bofs + arow;
  const short* Ap2 = A2 + bofs + arow;
  const short* Bp0 = B0 + bofs + brow; const short* Bp1 = B1 + bofs + brow;
  const short* Bp2 = B2 + bofs + brow;

  const int srow = tid >> 2;                              // staging row 0..127
  const int sslot = (tid & 3) ^ ((srow >> 1) & 3);        // pre-swizzled source k-slot

  auto stageT = [&](int kt, int sel){
    const int r = kt & 3;
    const int seg = kt >> 5;                              // 32 tiles per K-segment
    const int k0 = (kt & 31) * 32;
    const short* P = sel ? (seg == 0 ? Bp0 : (seg == 1 ? Bp1 : Bp2))
                         : (seg == 0 ? Ap0 : (seg == 1 ? Ap1 : Ap2));
    short* dbase = &lds[r][sel][0][0] + wid * 512;        // wave-uniform
    #pragma unroll
    for (int h = 0; h < 2; h++)
      gload_lds16(P + (size_t)(h * 128 + srow) * NDIM + k0 + sslot * 8,
                  dbase + h * 4096);
  };

  auto rdA = [&](int kt, int m) -> bf16x8 {
    const int rl = m * 16 + (lane & 15);
    const int p  = (lane >> 4) ^ ((rl >> 1) & 3);
    return *(const bf16x8*)(&lds[kt & 3][0][wr][0] + rl * 32 + p * 8);
  };
  auto rdB = [&](int kt, int n) -> bf16x8 {
    const int rb = wcl * 64 + n * 16 + (lane & 15);
    const int p  = (lane >> 4) ^ ((rb >> 1) & 3);
    return *(const bf16x8*)(&lds[kt & 3][1][rb >> 7][0] + (rb & 127) * 32 + p * 8);
  };

  f32x4 acc[8][4] = {};

  // prologue: stage tiles 0,1,2 (12 loads); retire tile 0's 4, then barrier
  stageT(0, 0); stageT(0, 1);
  stageT(1, 0); stageT(1, 1);
  stageT(2, 0); stageT(2, 1);
  asm volatile("s_waitcnt vmcnt(8)" ::: "memory");
  __builtin_amdgcn_s_barrier();

  for (int t = 0; t < nt; ++t){
    bf16x8 af[4], ag[4], bfr[4];

    // ---- read group 1 (6 reads): af0, af1, bfr0-3
    af[0] = rdA(t, 0); af[1] = rdA(t, 1);
    #pragma unroll
    for (int n = 0; n < 4; n++) bfr[n] = rdB(t, n);
    SBAR();

    // stage tile t+3 early: 4 vmcnt-class loads overlap all MFMA below
    if (t + 3 < nt){ stageT(t + 3, 0); stageT(t + 3, 1); }

    // ---- read group 2 (2 reads): af2, af3
    af[2] = rdA(t, 2); af[3] = rdA(t, 3);
    SBAR();
    // ---- read group 3 (4 reads): ag0-3
    #pragma unroll
    for (int m = 0; m < 4; m++) ag[m] = rdA(t, m + 4);
    SBAR();

    __builtin_amdgcn_s_setprio(1);
    // wait group 1 only (oldest 6 of 12); groups 2+3 + stage fly under MFMA
    asm volatile("s_waitcnt lgkmcnt(6)" ::: "memory");
    SBAR();
    #pragma unroll
    for (int m = 0; m < 2; m++)
      #pragma unroll
      for (int n = 0; n < 4; n++)
        MFMA_BF16(acc[m][n], af[m], bfr[n]);

    asm volatile("s_waitcnt lgkmcnt(4)" ::: "memory");
    SBAR();
    #pragma unroll
    for (int m = 2; m < 4; m++)
      #pragma unroll
      for (int n = 0; n < 4; n++)
        MFMA_BF16(acc[m][n], af[m], bfr[n]);

    // boundary vmcnt (counted, never 0 mid-loop) + final lgkm before last MFMA block
    if (t + 1 < nt){
      if (t + 3 < nt)      asm volatile("s_waitcnt vmcnt(8)" ::: "memory");
      else if (t + 2 < nt) asm volatile("s_waitcnt vmcnt(4)" ::: "memory");
      else                 asm volatile("s_waitcnt vmcnt(0)" ::: "memory");
    }
    asm volatile("s_waitcnt lgkmcnt(0)" ::: "memory");
    SBAR();
    #pragma unroll
    for (int m = 0; m < 4; m++)
      #pragma unroll
      for (int n = 0; n < 4; n++)
        MFMA_BF16(acc[m + 4][n], ag[m], bfr[n]);
    __builtin_amdgcn_s_setprio(0);

    __builtin_amdgcn_s_barrier();   // single per-tile gate (RAW t+1 / WAR t+4)
  }

  // epilogue: C/D layout col=lane&15, row=(lane>>4)*4+reg (m89)
  float* Cb = C + bofs;
  const int row0 = bx * 256 + wr * 128 + (lane >> 4) * 4;
  const int col0 = by * 256 + wcl * 64 + (lane & 15);
  #pragma unroll
  for (int m = 0; m < 8; m++)
    #pragma unroll
    for (int n = 0; n < 4; n++)
      #pragma unroll
      for (int r = 0; r < 4; r++)
        Cb[(size_t)(row0 + m * 16 + r) * NDIM + col0 + n * 16] = acc[m][n][r];
}

// -------- masked softmax over last dim, in-place on f32 weight; also emits bf16 copy.
__global__ __launch_bounds__(256) void k_softmax(float* __restrict__ w,
                                                 short* __restrict__ wbf,
                                                 const int* __restrict__ mask)
{
  const int gw   = blockIdx.x * 4 + (threadIdx.x >> 6);
  const int b    = gw >> 10;
  const int x    = gw & 1023;
  const int lane = threadIdx.x & 63;
  float* row  = w   + ((size_t)b * NDIM + x) * NDIM;
  short* rowb = wbf + ((size_t)b * NDIM + x) * NDIM;
  const int* mrow = mask + b * NDIM;

  f32x4 v[4]; i32x4 mk[4];
  float mx = -INFINITY;
  #pragma unroll
  for (int j = 0; j < 4; j++){
    const int c = j * 256 + lane * 4;
    v[j]  = *(const f32x4*)(row + c);
    mk[j] = *(const i32x4*)(mrow + c);
    #pragma unroll
    for (int e = 0; e < 4; e++)
      if (mk[j][e]) mx = fmaxf(mx, v[j][e]);
  }
  #pragma unroll
  for (int off = 32; off >= 1; off >>= 1) mx = fmaxf(mx, __shfl_xor(mx, off));

  float sum = 0.f;
  #pragma unroll
  for (int j = 0; j < 4; j++)
    #pragma unroll
    for (int e = 0; e < 4; e++){
      const float p = mk[j][e] ? __expf(v[j][e] - mx) : 0.f;
      v[j][e] = p; sum += p;
    }
  #pragma unroll
  for (int off = 32; off >= 1; off >>= 1) sum += __shfl_xor(sum, off);
  const float inv = sum > 0.f ? 1.f / sum : 0.f;

  #pragma unroll
  for (int j = 0; j < 4; j++){
    const int c = j * 256 + lane * 4;
    f32x4 o; short4_t ob;
    #pragma unroll
    for (int e = 0; e < 4; e++){
      const float p = v[j][e] * inv;
      o[e] = p; ob[e] = f2bf(p);
    }
    *(f32x4*)(row + c)  = o;
    *(short4_t*)(rowb + c) = ob;
  }
}

extern "C" void kernel_launch(void* const* d_in, const int* in_sizes, int n_in,
                              void* d_out, int out_size, void* d_ws, size_t ws_size,
                              hipStream_t stream)
{
  const float* xs   = (const float*)d_in[0];
  const float* ys   = (const float*)d_in[1];
  const int*   mask = (const int*)d_in[2];

  float* emb = (float*)d_out;            // [16,1024,1024] f32
  float* wgt = emb + (size_t)NEL;        // [16,1024,1024] f32

  // workspace (5 x NEL shorts = 168 MB)
  short* xs_hi = (short*)d_ws;
  short* xs_lo = xs_hi + NEL;
  short* ys_hi = xs_lo + NEL;
  short* ys_lo = ys_hi + NEL;
  short* ysT   = ys_lo + NEL;            // [b][d][y] bf16
  short* w_bf  = xs_hi;                  // alias: xs_hi/lo dead after GEMM1

  // 1. convert inputs (ys: split + transpose fused, single read pass)
  k_split<<<NEL / 1024, 256, 0, stream>>>(xs, xs_hi, xs_lo);
  k_split_ysT<<<dim3(16, 16, NBATCH), dim3(64, 8), 0, stream>>>(ys, ys_hi, ys_lo, ysT);
  // 2. scores = xs @ ys^T via virtual K=3072: hi*hi + hi*lo + lo*hi
  k_gemm256<0><<<256, 512, 0, stream>>>(xs_hi, xs_hi, xs_lo,
                                        ys_hi, ys_lo, ys_hi, wgt, 96);
  // 3. masked softmax in-place (+ bf16 copy into xs_hi region)
  k_softmax<<<(NBATCH * NDIM) / 4, 256, 0, stream>>>(wgt, w_bf, mask);
  // 4. emb = weight @ ys = w_bf @ ysT^T  (plain bf16, K=1024)
  k_gemm256<1><<<256, 512, 0, stream>>>(w_bf, w_bf, w_bf,
                                        ysT, ysT, ysT, emb, 32);
}